// Round 7
// baseline (304.331 us; speedup 1.0000x reference)
//
#include <hip/hip_runtime.h>

typedef unsigned short u16;
typedef __attribute__((ext_vector_type(8))) short short8;
typedef __attribute__((ext_vector_type(4))) short short4s;
typedef __attribute__((ext_vector_type(4))) float f32x4;

__device__ __forceinline__ u16 f2b(float f) {
  union { float f; unsigned u; } c; c.f = f;
  unsigned u = c.u;
  unsigned r = (u + 0x7FFFu + ((u >> 16) & 1u)) >> 16;
  return (u16)r;
}
__device__ __forceinline__ float b2f(u16 h) {
  union { unsigned u; float f; } c; c.u = ((unsigned)h) << 16;
  return c.f;
}

__device__ __forceinline__ void gload16(const u16* g, u16* l) {
  __builtin_amdgcn_global_load_lds((const __attribute__((address_space(1))) void*)g,
                                   (__attribute__((address_space(3))) void*)l, 16, 0, 0);
}

__device__ __forceinline__ short4s tr16(const u16* p) {
  short4s d;
  asm volatile("ds_read_b64_tr_b16 %0, %1"
               : "=v"(d)
               : "v"((const __attribute__((address_space(3))) u16*)p));
  return d;
}

#define MFMA(a, b, c) __builtin_amdgcn_mfma_f32_16x16x32_bf16(a, b, c, 0, 0, 0)

// ---------------- cast fp32 -> bf16 ----------------
__global__ __launch_bounds__(256) void cast_f32_bf16(const float4* __restrict__ in,
                                                     u16* __restrict__ out, int n4) {
  int i = blockIdx.x * 256 + threadIdx.x;
  if (i >= n4) return;
  float4 v = in[i];
  ushort4 r;
  r.x = f2b(v.x); r.y = f2b(v.y); r.z = f2b(v.z); r.w = f2b(v.w);
  *(ushort4*)(out + (size_t)i * 4) = r;
}

// ---------------- RoPE in-place on K region only (cols 2048..4095) --------
__global__ __launch_bounds__(256) void rope_k(u16* __restrict__ qkv,
                                              const float* __restrict__ fc,
                                              const float* __restrict__ fs) {
  int idx = blockIdx.x * 256 + threadIdx.x;   // 4096 rows * 256 chunks
  int m = idx >> 8;
  int c = idx & 255;
  int s = m & 2047;
  int i0 = (c * 4) & 63;
  u16* p = qkv + (size_t)m * 6144 + 2048 + c * 8;
  short8 v = *(short8*)p;
  float4 cs = *(const float4*)(fc + (size_t)s * 64 + i0);
  float4 sn = *(const float4*)(fs + (size_t)s * 64 + i0);
  float cc[4] = {cs.x, cs.y, cs.z, cs.w};
  float ss[4] = {sn.x, sn.y, sn.z, sn.w};
#pragma unroll
  for (int t = 0; t < 4; ++t) {
    float x0 = b2f((u16)v[2 * t]);
    float x1 = b2f((u16)v[2 * t + 1]);
    float o0 = x0 * cc[t] - x1 * ss[t];
    float o1 = x0 * ss[t] + x1 * cc[t];
    v[2 * t]     = (short)f2b(o0);
    v[2 * t + 1] = (short)f2b(o1);
  }
  *(short8*)p = v;
}

// ---------------- 128x256 2-phase bf16 NT GEMM, BK=32 (unchanged R5) ------
template <int F32OUT>
__global__ __launch_bounds__(512, 4) void gemm_nt_2ph(const u16* __restrict__ Ag,
                                                      const u16* __restrict__ Bg,
                                                      void* __restrict__ Cp,
                                                      int M, int N, int K) {
  __shared__ __align__(16) u16 lds[24576];
  const int tid = threadIdx.x;
  const int l = tid & 63, w = tid >> 6;
  const int wm = w >> 2, wn = w & 3;
  const int ln = l & 15, lk = l >> 4;
  const int nbn = N >> 8;
  const int nwg = (M >> 7) * nbn;
  const int wg = ((blockIdx.x & 7) * (nwg >> 3)) + (blockIdx.x >> 3);
  const int row0 = (wg / nbn) << 7;
  const int col0 = (wg % nbn) << 8;
  const int T = K >> 5;

  const int r0s = tid >> 2;
  const int j0s = ((tid & 3) ^ (r0s & 3)) << 3;

#define STAGE_A(t)                                                                    \
  gload16(Ag + (size_t)(row0 + r0s) * K + (t) * 32 + j0s,                             \
          lds + ((t) & 1) * 4096 + tid * 8);
#define STAGE_B(t, h)                                                                 \
  gload16(Bg + (size_t)(col0 + (h) * 128 + r0s) * K + (t) * 32 + j0s,                 \
          lds + 8192 + ((t) & 1) * 8192 + (h) * 4096 + tid * 8);

  f32x4 acc[4][4];
#pragma unroll
  for (int m = 0; m < 4; ++m)
#pragma unroll
    for (int n = 0; n < 4; ++n) acc[m][n] = (f32x4){0.f, 0.f, 0.f, 0.f};

  const int cx = ((lk ^ (ln & 3)) << 3);

  STAGE_A(0); STAGE_B(0, 0); STAGE_B(0, 1);
  STAGE_A(1); STAGE_B(1, 0); STAGE_B(1, 1);
  asm volatile("s_waitcnt vmcnt(3)" ::: "memory");
  __builtin_amdgcn_s_barrier();

  for (int t = 0; t < T; ++t) {
    const u16* aB = lds + (t & 1) * 4096;
    const u16* bB = lds + 8192 + (t & 1) * 8192 + (wn >> 1) * 4096;
    short8 bf[4];
    short8 af[2];
#pragma unroll
    for (int q = 0; q < 2; ++q) {
      if (q == 0) {
#pragma unroll
        for (int n = 0; n < 4; ++n)
          bf[n] = *(const short8*)&bB[((wn & 1) * 64 + n * 16 + ln) * 32 + cx];
      }
#pragma unroll
      for (int m2 = 0; m2 < 2; ++m2)
        af[m2] = *(const short8*)&aB[(wm * 64 + (q * 2 + m2) * 16 + ln) * 32 + cx];
      if (q == 0) {
        if (t >= 1 && t + 1 < T) STAGE_A(t + 1);
      } else {
        if (t + 2 < T) {
          STAGE_B(t + 2, 0);
          STAGE_B(t + 2, 1);
          asm volatile("s_waitcnt vmcnt(2)" ::: "memory");
        } else if (t + 1 < T) {
          asm volatile("s_waitcnt vmcnt(0)" ::: "memory");
        }
      }
      __builtin_amdgcn_sched_barrier(0);
      __builtin_amdgcn_s_barrier();
      __builtin_amdgcn_sched_barrier(0);
      __builtin_amdgcn_s_setprio(1);
#pragma unroll
      for (int m2 = 0; m2 < 2; ++m2)
#pragma unroll
        for (int n = 0; n < 4; ++n)
          acc[q * 2 + m2][n] = MFMA(af[m2], bf[n], acc[q * 2 + m2][n]);
      __builtin_amdgcn_s_setprio(0);
      __builtin_amdgcn_sched_barrier(0);
      __builtin_amdgcn_s_barrier();
      __builtin_amdgcn_sched_barrier(0);
    }
  }

#pragma unroll
  for (int m = 0; m < 4; ++m) {
    int r0 = row0 + wm * 64 + m * 16 + lk * 4;
#pragma unroll
    for (int n = 0; n < 4; ++n) {
      int cc = col0 + wn * 64 + n * 16 + ln;
#pragma unroll
      for (int j = 0; j < 4; ++j) {
        float v = acc[m][n][j];
        if (F32OUT) ((float*)Cp)[(size_t)(r0 + j) * N + cc] = v;
        else        ((u16*)Cp)[(size_t)(r0 + j) * N + cc]   = f2b(v);
      }
    }
  }
#undef STAGE_A
#undef STAGE_B
}

// ---------------- flash attention: causal, hd=128, H=16 ----------------
// R5-proven structure + (a) Q in-register RoPE with 1/sqrt(hd) folded into
// cos/sin, (b) defer-max (THR=8) rescale skip. P-path = R5 (row-major sP,
// f2b stores, shfl row-sum).
__global__ __launch_bounds__(256) void attn_fwd(const u16* __restrict__ qkv,
                                                const float* __restrict__ fc,
                                                const float* __restrict__ fs,
                                                u16* __restrict__ out) {
  __shared__ __align__(16) u16 sK[2][64 * 128];
  __shared__ __align__(16) u16 sV[2][64 * 128];
  __shared__ __align__(16) u16 sP[4][16 * 72];
  const int tid = threadIdx.x, l = tid & 63, w = tid >> 6;
  const int ln = l & 15, lk = l >> 4;

  const int bid = blockIdx.x;
  const int l0 = ((bid & 7) << 6) + (bid >> 3);   // XCD-cluster
  const int bh = l0 >> 4, pr = l0 & 15;
  const int b = bh >> 4, h = bh & 15;

  const u16* Kp = qkv + (size_t)b * 2048 * 6144 + 2048 + h * 128;
  const u16* Vp = Kp + 2048;
  const float scale = 0.08838834764831845f;  // 1/sqrt(128)

  for (int pass = 0; pass < 2; ++pass) {
    const int qt = pass ? (31 - pr) : pr;
    const int m0 = b * 2048 + qt * 64;
    const u16* Qp = qkv + (size_t)m0 * 6144 + h * 128;
    const int srow = qt * 64 + w * 16 + ln;   // seq pos of this lane's q-row

    // Q load + in-register RoPE, scale folded into cos/sin
    short8 qf[4];
#pragma unroll
    for (int kc = 0; kc < 4; ++kc) {
      short8 raw = *(const short8*)(Qp + (size_t)(w * 16 + ln) * 6144 + kc * 32 + lk * 8);
      float4 c4 = *(const float4*)(fc + (size_t)srow * 64 + kc * 16 + lk * 4);
      float4 s4 = *(const float4*)(fs + (size_t)srow * 64 + kc * 16 + lk * 4);
      float cc[4] = {c4.x * scale, c4.y * scale, c4.z * scale, c4.w * scale};
      float ss[4] = {s4.x * scale, s4.y * scale, s4.z * scale, s4.w * scale};
#pragma unroll
      for (int t = 0; t < 4; ++t) {
        float x0 = b2f((u16)raw[2 * t]);
        float x1 = b2f((u16)raw[2 * t + 1]);
        qf[kc][2 * t]     = (short)f2b(x0 * cc[t] - x1 * ss[t]);
        qf[kc][2 * t + 1] = (short)f2b(x0 * ss[t] + x1 * cc[t]);
      }
    }

    f32x4 o[8];
#pragma unroll
    for (int d = 0; d < 8; ++d) o[d] = (f32x4){0.f, 0.f, 0.f, 0.f};
    float mrow[4] = {-1e9f, -1e9f, -1e9f, -1e9f};
    float lsum[4] = {0.f, 0.f, 0.f, 0.f};

    const int ntl = qt + 1;

    // prologue: stage tile 0 into buffer 0
    {
#pragma unroll
      for (int q = 0; q < 4; ++q) {
        int e = q * 256 + tid;
        int r = e >> 4, p = e & 15;
        gload16(Kp + (size_t)r * 6144 + ((p ^ (r & 7)) << 3), &sK[0][e * 8]);
        int j = ((e >> 6) << 2) + ((e & 7) >> 1);
        int d = (((e >> 3) & 7) << 4) + ((e & 1) << 3);
        gload16(Vp + (size_t)j * 6144 + d, &sV[0][e * 8]);
      }
    }
    __syncthreads();

    int cur = 0;
    for (int jt = 0; jt < ntl; ++jt) {
      if (jt + 1 < ntl) {
        const u16* Kt = Kp + (size_t)(jt + 1) * 64 * 6144;
        const u16* Vt = Vp + (size_t)(jt + 1) * 64 * 6144;
        int nb = cur ^ 1;
#pragma unroll
        for (int q = 0; q < 4; ++q) {
          int e = q * 256 + tid;
          int r = e >> 4, p = e & 15;
          gload16(Kt + (size_t)r * 6144 + ((p ^ (r & 7)) << 3), &sK[nb][e * 8]);
          int j = ((e >> 6) << 2) + ((e & 7) >> 1);
          int d = (((e >> 3) & 7) << 4) + ((e & 1) << 3);
          gload16(Vt + (size_t)j * 6144 + d, &sV[nb][e * 8]);
        }
      }

      // ---- QK^T (Q pre-scaled) ----
      f32x4 sf[4];
#pragma unroll
      for (int nc = 0; nc < 4; ++nc) {
        f32x4 s = (f32x4){0.f, 0.f, 0.f, 0.f};
#pragma unroll
        for (int kc = 0; kc < 4; ++kc) {
          int r = nc * 16 + ln;
          short8 kb = *(const short8*)&sK[cur][r * 128 + (((kc << 2) + lk) ^ (r & 7)) * 8];
          s = MFMA(qf[kc], kb, s);
        }
        sf[nc] = s;
      }

      // causal mask on diagonal tile only (no scale needed — Q pre-scaled)
      if (jt == qt) {
        int ig = w * 16 + lk * 4;
#pragma unroll
        for (int nc = 0; nc < 4; ++nc) {
          int jg = nc * 16 + ln;
#pragma unroll
          for (int j = 0; j < 4; ++j)
            sf[nc][j] = (jg > ig + j) ? -1e9f : sf[nc][j];
        }
      }

      // ---- running max (16-lane reduce) + defer-max rescale ----
      float tm[4];
#pragma unroll
      for (int j = 0; j < 4; ++j)
        tm[j] = fmaxf(fmaxf(sf[0][j], sf[1][j]), fmaxf(sf[2][j], sf[3][j]));
#pragma unroll
      for (int off = 1; off < 16; off <<= 1)
#pragma unroll
        for (int j = 0; j < 4; ++j) tm[j] = fmaxf(tm[j], __shfl_xor(tm[j], off, 16));

      int ok = (tm[0] <= mrow[0] + 8.f) & (tm[1] <= mrow[1] + 8.f) &
               (tm[2] <= mrow[2] + 8.f) & (tm[3] <= mrow[3] + 8.f);
      if (!__all(ok)) {
        float al[4];
#pragma unroll
        for (int j = 0; j < 4; ++j) {
          float nm = fmaxf(mrow[j], tm[j]);
          al[j] = __expf(mrow[j] - nm);
          mrow[j] = nm;
        }
#pragma unroll
        for (int d = 0; d < 8; ++d)
#pragma unroll
          for (int j = 0; j < 4; ++j) o[d][j] *= al[j];
#pragma unroll
        for (int j = 0; j < 4; ++j) lsum[j] *= al[j];
      }

      // ---- P = exp(S - m): R5 path (row-major sP + f2b + shfl row-sum) ----
      float rs[4] = {0.f, 0.f, 0.f, 0.f};
#pragma unroll
      for (int nc = 0; nc < 4; ++nc)
#pragma unroll
        for (int j = 0; j < 4; ++j) {
          float p = __expf(sf[nc][j] - mrow[j]);
          u16 pb = f2b(p);
          sP[w][(lk * 4 + j) * 72 + nc * 16 + ln] = pb;
          rs[j] += b2f(pb);
        }
#pragma unroll
      for (int off = 1; off < 16; off <<= 1)
#pragma unroll
        for (int j = 0; j < 4; ++j) rs[j] += __shfl_xor(rs[j], off, 16);
#pragma unroll
      for (int j = 0; j < 4; ++j) lsum[j] += rs[j];

      // ---- PV via transpose reads of subtiled sV ----
      short8 pa0 = *(const short8*)&sP[w][ln * 72 + lk * 8];
      short8 pa1 = *(const short8*)&sP[w][ln * 72 + 32 + lk * 8];
#pragma unroll
      for (int dblk = 0; dblk < 8; ++dblk) {
        const u16* b0 = &sV[cur][(lk * 2) * 512 + dblk * 64 + ln * 4];
        const u16* b1 = b0 + 8 * 512;
        short4s t00 = tr16(b0);
        short4s t01 = tr16(b0 + 512);
        short4s t10 = tr16(b1);
        short4s t11 = tr16(b1 + 512);
        asm volatile("s_waitcnt lgkmcnt(0)" ::: "memory");
        __builtin_amdgcn_sched_barrier(0);
        short8 vb0 = {t00[0], t00[1], t00[2], t00[3], t01[0], t01[1], t01[2], t01[3]};
        short8 vb1 = {t10[0], t10[1], t10[2], t10[3], t11[0], t11[1], t11[2], t11[3]};
        o[dblk] = MFMA(pa0, vb0, o[dblk]);
        o[dblk] = MFMA(pa1, vb1, o[dblk]);
      }

      __syncthreads();
      cur ^= 1;
    }

    float inv[4];
#pragma unroll
    for (int j = 0; j < 4; ++j) inv[j] = 1.f / lsum[j];
#pragma unroll
    for (int d = 0; d < 8; ++d)
#pragma unroll
      for (int j = 0; j < 4; ++j)
        out[(size_t)(m0 + w * 16 + lk * 4 + j) * 2048 + h * 128 + d * 16 + ln] =
            f2b(o[d][j] * inv[j]);
  }
}

extern "C" void kernel_launch(void* const* d_in, const int* in_sizes, int n_in,
                              void* d_out, int out_size, void* d_ws, size_t ws_size,
                              hipStream_t stream) {
  const float* x  = (const float*)d_in[0];
  const float* wq = (const float*)d_in[1];
  const float* wk = (const float*)d_in[2];
  const float* wv = (const float*)d_in[3];
  const float* wo = (const float*)d_in[4];
  const float* fc = (const float*)d_in[5];
  const float* fs = (const float*)d_in[6];

  char* ws = (char*)d_ws;
  u16* xb   = (u16*)(ws);
  u16* wqkv = (u16*)(ws + 16777216);
  u16* wob  = (u16*)(ws + 41943040);
  u16* qkv  = (u16*)(ws + 50331648);
  u16* aout = (u16*)(ws + 100663296);

  cast_f32_bf16<<<8192, 256, 0, stream>>>((const float4*)x, xb, 2097152);
  cast_f32_bf16<<<4096, 256, 0, stream>>>((const float4*)wq, wqkv, 1048576);
  cast_f32_bf16<<<4096, 256, 0, stream>>>((const float4*)wk, wqkv + 4194304, 1048576);
  cast_f32_bf16<<<4096, 256, 0, stream>>>((const float4*)wv, wqkv + 8388608, 1048576);
  cast_f32_bf16<<<4096, 256, 0, stream>>>((const float4*)wo, wob, 1048576);

  gemm_nt_2ph<0><<<768, 512, 0, stream>>>(xb, wqkv, qkv, 4096, 6144, 2048);
  rope_k<<<4096, 256, 0, stream>>>(qkv, fc, fs);
  attn_fwd<<<512, 256, 0, stream>>>(qkv, fc, fs, aout);
  gemm_nt_2ph<1><<<256, 512, 0, stream>>>(aout, wob, d_out, 4096, 2048, 2048);
}

// Round 8
// 279.562 us; speedup vs baseline: 1.0886x; 1.0886x over previous
//
#include <hip/hip_runtime.h>

typedef unsigned short u16;
typedef __attribute__((ext_vector_type(8))) short short8;
typedef __attribute__((ext_vector_type(4))) short short4s;
typedef __attribute__((ext_vector_type(4))) float f32x4;

__device__ __forceinline__ u16 f2b(float f) {
  union { float f; unsigned u; } c; c.f = f;
  unsigned u = c.u;
  unsigned r = (u + 0x7FFFu + ((u >> 16) & 1u)) >> 16;
  return (u16)r;
}
__device__ __forceinline__ float b2f(u16 h) {
  union { unsigned u; float f; } c; c.u = ((unsigned)h) << 16;
  return c.f;
}

__device__ __forceinline__ void gload16(const u16* g, u16* l) {
  __builtin_amdgcn_global_load_lds((const __attribute__((address_space(1))) void*)g,
                                   (__attribute__((address_space(3))) void*)l, 16, 0, 0);
}

__device__ __forceinline__ short4s tr16(const u16* p) {
  short4s d;
  asm volatile("ds_read_b64_tr_b16 %0, %1"
               : "=v"(d)
               : "v"((const __attribute__((address_space(3))) u16*)p));
  return d;
}

#define MFMA(a, b, c) __builtin_amdgcn_mfma_f32_16x16x32_bf16(a, b, c, 0, 0, 0)

// ---------------- cast fp32 -> bf16 ----------------
__global__ __launch_bounds__(256) void cast_f32_bf16(const float4* __restrict__ in,
                                                     u16* __restrict__ out, int n4) {
  int i = blockIdx.x * 256 + threadIdx.x;
  if (i >= n4) return;
  float4 v = in[i];
  ushort4 r;
  r.x = f2b(v.x); r.y = f2b(v.y); r.z = f2b(v.z); r.w = f2b(v.w);
  *(ushort4*)(out + (size_t)i * 4) = r;
}

// ---------------- RoPE in-place on K region only (cols 2048..4095) --------
__global__ __launch_bounds__(256) void rope_k(u16* __restrict__ qkv,
                                              const float* __restrict__ fc,
                                              const float* __restrict__ fs) {
  int idx = blockIdx.x * 256 + threadIdx.x;
  int m = idx >> 8;
  int c = idx & 255;
  int s = m & 2047;
  int i0 = (c * 4) & 63;
  u16* p = qkv + (size_t)m * 6144 + 2048 + c * 8;
  short8 v = *(short8*)p;
  float4 cs = *(const float4*)(fc + (size_t)s * 64 + i0);
  float4 sn = *(const float4*)(fs + (size_t)s * 64 + i0);
  float cc[4] = {cs.x, cs.y, cs.z, cs.w};
  float ss[4] = {sn.x, sn.y, sn.z, sn.w};
#pragma unroll
  for (int t = 0; t < 4; ++t) {
    float x0 = b2f((u16)v[2 * t]);
    float x1 = b2f((u16)v[2 * t + 1]);
    float o0 = x0 * cc[t] - x1 * ss[t];
    float o1 = x0 * ss[t] + x1 * cc[t];
    v[2 * t]     = (short)f2b(o0);
    v[2 * t + 1] = (short)f2b(o1);
  }
  *(short8*)p = v;
}

// ---------------- 128x256 2-phase bf16 NT GEMM, BK=32 (unchanged) ---------
template <int F32OUT>
__global__ __launch_bounds__(512, 4) void gemm_nt_2ph(const u16* __restrict__ Ag,
                                                      const u16* __restrict__ Bg,
                                                      void* __restrict__ Cp,
                                                      int M, int N, int K) {
  __shared__ __align__(16) u16 lds[24576];
  const int tid = threadIdx.x;
  const int l = tid & 63, w = tid >> 6;
  const int wm = w >> 2, wn = w & 3;
  const int ln = l & 15, lk = l >> 4;
  const int nbn = N >> 8;
  const int nwg = (M >> 7) * nbn;
  const int wg = ((blockIdx.x & 7) * (nwg >> 3)) + (blockIdx.x >> 3);
  const int row0 = (wg / nbn) << 7;
  const int col0 = (wg % nbn) << 8;
  const int T = K >> 5;

  const int r0s = tid >> 2;
  const int j0s = ((tid & 3) ^ (r0s & 3)) << 3;

#define STAGE_A(t)                                                                    \
  gload16(Ag + (size_t)(row0 + r0s) * K + (t) * 32 + j0s,                             \
          lds + ((t) & 1) * 4096 + tid * 8);
#define STAGE_B(t, h)                                                                 \
  gload16(Bg + (size_t)(col0 + (h) * 128 + r0s) * K + (t) * 32 + j0s,                 \
          lds + 8192 + ((t) & 1) * 8192 + (h) * 4096 + tid * 8);

  f32x4 acc[4][4];
#pragma unroll
  for (int m = 0; m < 4; ++m)
#pragma unroll
    for (int n = 0; n < 4; ++n) acc[m][n] = (f32x4){0.f, 0.f, 0.f, 0.f};

  const int cx = ((lk ^ (ln & 3)) << 3);

  STAGE_A(0); STAGE_B(0, 0); STAGE_B(0, 1);
  STAGE_A(1); STAGE_B(1, 0); STAGE_B(1, 1);
  asm volatile("s_waitcnt vmcnt(3)" ::: "memory");
  __builtin_amdgcn_s_barrier();

  for (int t = 0; t < T; ++t) {
    const u16* aB = lds + (t & 1) * 4096;
    const u16* bB = lds + 8192 + (t & 1) * 8192 + (wn >> 1) * 4096;
    short8 bf[4];
    short8 af[2];
#pragma unroll
    for (int q = 0; q < 2; ++q) {
      if (q == 0) {
#pragma unroll
        for (int n = 0; n < 4; ++n)
          bf[n] = *(const short8*)&bB[((wn & 1) * 64 + n * 16 + ln) * 32 + cx];
      }
#pragma unroll
      for (int m2 = 0; m2 < 2; ++m2)
        af[m2] = *(const short8*)&aB[(wm * 64 + (q * 2 + m2) * 16 + ln) * 32 + cx];
      if (q == 0) {
        if (t >= 1 && t + 1 < T) STAGE_A(t + 1);
      } else {
        if (t + 2 < T) {
          STAGE_B(t + 2, 0);
          STAGE_B(t + 2, 1);
          asm volatile("s_waitcnt vmcnt(2)" ::: "memory");
        } else if (t + 1 < T) {
          asm volatile("s_waitcnt vmcnt(0)" ::: "memory");
        }
      }
      __builtin_amdgcn_sched_barrier(0);
      __builtin_amdgcn_s_barrier();
      __builtin_amdgcn_sched_barrier(0);
      __builtin_amdgcn_s_setprio(1);
#pragma unroll
      for (int m2 = 0; m2 < 2; ++m2)
#pragma unroll
        for (int n = 0; n < 4; ++n)
          acc[q * 2 + m2][n] = MFMA(af[m2], bf[n], acc[q * 2 + m2][n]);
      __builtin_amdgcn_s_setprio(0);
      __builtin_amdgcn_sched_barrier(0);
      __builtin_amdgcn_s_barrier();
      __builtin_amdgcn_sched_barrier(0);
    }
  }

#pragma unroll
  for (int m = 0; m < 4; ++m) {
    int r0 = row0 + wm * 64 + m * 16 + lk * 4;
#pragma unroll
    for (int n = 0; n < 4; ++n) {
      int cc = col0 + wn * 64 + n * 16 + ln;
#pragma unroll
      for (int j = 0; j < 4; ++j) {
        float v = acc[m][n][j];
        if (F32OUT) ((float*)Cp)[(size_t)(r0 + j) * N + cc] = v;
        else        ((u16*)Cp)[(size_t)(r0 + j) * N + cc]   = f2b(v);
      }
    }
  }
#undef STAGE_A
#undef STAGE_B
}

// ---------------- flash attention: causal, hd=128, H=16 ----------------
// R7 + latency fixes: (1) PV 2-deep pipelined tr16 (counted lgkmcnt(8),
// 4-slot WAR-safe buffer); (2) per-tile shfl chains removed — row-sum is
// per-lane partial reduced once after the KV loop; max-shfl only on the
// rare defer-max slow path; (3) setprio around MFMA clusters.
__global__ __launch_bounds__(256) void attn_fwd(const u16* __restrict__ qkv,
                                                const float* __restrict__ fc,
                                                const float* __restrict__ fs,
                                                u16* __restrict__ out) {
  __shared__ __align__(16) u16 sK[2][64 * 128];
  __shared__ __align__(16) u16 sV[2][64 * 128];
  __shared__ __align__(16) u16 sP[4][16 * 72];
  const int tid = threadIdx.x, l = tid & 63, w = tid >> 6;
  const int ln = l & 15, lk = l >> 4;

  const int bid = blockIdx.x;
  const int l0 = ((bid & 7) << 6) + (bid >> 3);   // XCD-cluster
  const int bh = l0 >> 4, pr = l0 & 15;
  const int b = bh >> 4, h = bh & 15;

  const u16* Kp = qkv + (size_t)b * 2048 * 6144 + 2048 + h * 128;
  const u16* Vp = Kp + 2048;
  const float scale = 0.08838834764831845f;  // 1/sqrt(128)

  for (int pass = 0; pass < 2; ++pass) {
    const int qt = pass ? (31 - pr) : pr;
    const int m0 = b * 2048 + qt * 64;
    const u16* Qp = qkv + (size_t)m0 * 6144 + h * 128;
    const int srow = qt * 64 + w * 16 + ln;

    // Q load + in-register RoPE, scale folded into cos/sin
    short8 qf[4];
#pragma unroll
    for (int kc = 0; kc < 4; ++kc) {
      short8 raw = *(const short8*)(Qp + (size_t)(w * 16 + ln) * 6144 + kc * 32 + lk * 8);
      float4 c4 = *(const float4*)(fc + (size_t)srow * 64 + kc * 16 + lk * 4);
      float4 s4 = *(const float4*)(fs + (size_t)srow * 64 + kc * 16 + lk * 4);
      float cc[4] = {c4.x * scale, c4.y * scale, c4.z * scale, c4.w * scale};
      float ss[4] = {s4.x * scale, s4.y * scale, s4.z * scale, s4.w * scale};
#pragma unroll
      for (int t = 0; t < 4; ++t) {
        float x0 = b2f((u16)raw[2 * t]);
        float x1 = b2f((u16)raw[2 * t + 1]);
        qf[kc][2 * t]     = (short)f2b(x0 * cc[t] - x1 * ss[t]);
        qf[kc][2 * t + 1] = (short)f2b(x0 * ss[t] + x1 * cc[t]);
      }
    }

    f32x4 o[8];
#pragma unroll
    for (int d = 0; d < 8; ++d) o[d] = (f32x4){0.f, 0.f, 0.f, 0.f};
    float mrow[4] = {-1e9f, -1e9f, -1e9f, -1e9f};
    float lsum[4] = {0.f, 0.f, 0.f, 0.f};   // PER-LANE partial row sums

    const int ntl = qt + 1;

    {
#pragma unroll
      for (int q = 0; q < 4; ++q) {
        int e = q * 256 + tid;
        int r = e >> 4, p = e & 15;
        gload16(Kp + (size_t)r * 6144 + ((p ^ (r & 7)) << 3), &sK[0][e * 8]);
        int j = ((e >> 6) << 2) + ((e & 7) >> 1);
        int d = (((e >> 3) & 7) << 4) + ((e & 1) << 3);
        gload16(Vp + (size_t)j * 6144 + d, &sV[0][e * 8]);
      }
    }
    __syncthreads();

    int cur = 0;
    for (int jt = 0; jt < ntl; ++jt) {
      if (jt + 1 < ntl) {
        const u16* Kt = Kp + (size_t)(jt + 1) * 64 * 6144;
        const u16* Vt = Vp + (size_t)(jt + 1) * 64 * 6144;
        int nb = cur ^ 1;
#pragma unroll
        for (int q = 0; q < 4; ++q) {
          int e = q * 256 + tid;
          int r = e >> 4, p = e & 15;
          gload16(Kt + (size_t)r * 6144 + ((p ^ (r & 7)) << 3), &sK[nb][e * 8]);
          int j = ((e >> 6) << 2) + ((e & 7) >> 1);
          int d = (((e >> 3) & 7) << 4) + ((e & 1) << 3);
          gload16(Vt + (size_t)j * 6144 + d, &sV[nb][e * 8]);
        }
      }

      // ---- QK^T (Q pre-scaled) ----
      f32x4 sf[4];
      __builtin_amdgcn_s_setprio(1);
#pragma unroll
      for (int nc = 0; nc < 4; ++nc) {
        f32x4 s = (f32x4){0.f, 0.f, 0.f, 0.f};
#pragma unroll
        for (int kc = 0; kc < 4; ++kc) {
          int r = nc * 16 + ln;
          short8 kb = *(const short8*)&sK[cur][r * 128 + (((kc << 2) + lk) ^ (r & 7)) * 8];
          s = MFMA(qf[kc], kb, s);
        }
        sf[nc] = s;
      }
      __builtin_amdgcn_s_setprio(0);

      // causal mask on diagonal tile only
      if (jt == qt) {
        int ig = w * 16 + lk * 4;
#pragma unroll
        for (int nc = 0; nc < 4; ++nc) {
          int jg = nc * 16 + ln;
#pragma unroll
          for (int j = 0; j < 4; ++j)
            sf[nc][j] = (jg > ig + j) ? -1e9f : sf[nc][j];
        }
      }

      // ---- defer-max: fast path has NO cross-lane reduce ----
      float tm[4];
#pragma unroll
      for (int j = 0; j < 4; ++j)
        tm[j] = fmaxf(fmaxf(sf[0][j], sf[1][j]), fmaxf(sf[2][j], sf[3][j]));
      int ok = (tm[0] <= mrow[0] + 8.f) & (tm[1] <= mrow[1] + 8.f) &
               (tm[2] <= mrow[2] + 8.f) & (tm[3] <= mrow[3] + 8.f);
      if (!__all(ok)) {
        // slow path: full 16-lane max reduce + rescale
#pragma unroll
        for (int off = 1; off < 16; off <<= 1)
#pragma unroll
          for (int j = 0; j < 4; ++j) tm[j] = fmaxf(tm[j], __shfl_xor(tm[j], off, 16));
        float al[4];
#pragma unroll
        for (int j = 0; j < 4; ++j) {
          float nm = fmaxf(mrow[j], tm[j]);
          al[j] = __expf(mrow[j] - nm);
          mrow[j] = nm;
        }
#pragma unroll
        for (int d = 0; d < 8; ++d)
#pragma unroll
          for (int j = 0; j < 4; ++j) o[d][j] *= al[j];
#pragma unroll
        for (int j = 0; j < 4; ++j) lsum[j] *= al[j];
      }

      // ---- P = exp(S - m); per-lane partial row-sum (no shfl) ----
#pragma unroll
      for (int nc = 0; nc < 4; ++nc)
#pragma unroll
        for (int j = 0; j < 4; ++j) {
          float p = __expf(sf[nc][j] - mrow[j]);
          u16 pb = f2b(p);
          sP[w][(lk * 4 + j) * 72 + nc * 16 + ln] = pb;
          lsum[j] += b2f(pb);
        }

      // ---- PV: 2-deep pipelined tr16 reads, counted lgkmcnt ----
      short8 pa0 = *(const short8*)&sP[w][ln * 72 + lk * 8];
      short8 pa1 = *(const short8*)&sP[w][ln * 72 + 32 + lk * 8];
      asm volatile("s_waitcnt lgkmcnt(0)" ::: "memory");
      __builtin_amdgcn_sched_barrier(0);

      short4s tb[4][4];
#define TRISSUE(dblk, slot)                                                  \
      {                                                                      \
        const u16* vb = &sV[cur][(lk * 2) * 512 + (dblk) * 64 + ln * 4];     \
        tb[slot][0] = tr16(vb);                                              \
        tb[slot][1] = tr16(vb + 512);                                        \
        tb[slot][2] = tr16(vb + 4096);                                       \
        tb[slot][3] = tr16(vb + 4096 + 512);                                 \
      }
      TRISSUE(0, 0);
      TRISSUE(1, 1);
      __builtin_amdgcn_s_setprio(1);
#pragma unroll
      for (int d = 0; d < 8; ++d) {
        if (d < 6) TRISSUE(d + 2, (d + 2) & 3);
        if (d < 6)       asm volatile("s_waitcnt lgkmcnt(8)" ::: "memory");
        else if (d == 6) asm volatile("s_waitcnt lgkmcnt(4)" ::: "memory");
        else             asm volatile("s_waitcnt lgkmcnt(0)" ::: "memory");
        __builtin_amdgcn_sched_barrier(0);
        short8 vb0 = {tb[d & 3][0][0], tb[d & 3][0][1], tb[d & 3][0][2], tb[d & 3][0][3],
                      tb[d & 3][1][0], tb[d & 3][1][1], tb[d & 3][1][2], tb[d & 3][1][3]};
        short8 vb1 = {tb[d & 3][2][0], tb[d & 3][2][1], tb[d & 3][2][2], tb[d & 3][2][3],
                      tb[d & 3][3][0], tb[d & 3][3][1], tb[d & 3][3][2], tb[d & 3][3][3]};
        o[d] = MFMA(pa0, vb0, o[d]);
        o[d] = MFMA(pa1, vb1, o[d]);
      }
      __builtin_amdgcn_s_setprio(0);
#undef TRISSUE

      __syncthreads();
      cur ^= 1;
    }

    // final row-sum reduce (once per Q-tile) + normalize + store
#pragma unroll
    for (int off = 1; off < 16; off <<= 1)
#pragma unroll
      for (int j = 0; j < 4; ++j) lsum[j] += __shfl_xor(lsum[j], off, 16);
    float inv[4];
#pragma unroll
    for (int j = 0; j < 4; ++j) inv[j] = 1.f / lsum[j];
#pragma unroll
    for (int d = 0; d < 8; ++d)
#pragma unroll
      for (int j = 0; j < 4; ++j)
        out[(size_t)(m0 + w * 16 + lk * 4 + j) * 2048 + h * 128 + d * 16 + ln] =
            f2b(o[d][j] * inv[j]);
  }
}

extern "C" void kernel_launch(void* const* d_in, const int* in_sizes, int n_in,
                              void* d_out, int out_size, void* d_ws, size_t ws_size,
                              hipStream_t stream) {
  const float* x  = (const float*)d_in[0];
  const float* wq = (const float*)d_in[1];
  const float* wk = (const float*)d_in[2];
  const float* wv = (const float*)d_in[3];
  const float* wo = (const float*)d_in[4];
  const float* fc = (const float*)d_in[5];
  const float* fs = (const float*)d_in[6];

  char* ws = (char*)d_ws;
  u16* xb   = (u16*)(ws);
  u16* wqkv = (u16*)(ws + 16777216);
  u16* wob  = (u16*)(ws + 41943040);
  u16* qkv  = (u16*)(ws + 50331648);
  u16* aout = (u16*)(ws + 100663296);

  cast_f32_bf16<<<8192, 256, 0, stream>>>((const float4*)x, xb, 2097152);
  cast_f32_bf16<<<4096, 256, 0, stream>>>((const float4*)wq, wqkv, 1048576);
  cast_f32_bf16<<<4096, 256, 0, stream>>>((const float4*)wk, wqkv + 4194304, 1048576);
  cast_f32_bf16<<<4096, 256, 0, stream>>>((const float4*)wv, wqkv + 8388608, 1048576);
  cast_f32_bf16<<<4096, 256, 0, stream>>>((const float4*)wo, wob, 1048576);

  gemm_nt_2ph<0><<<768, 512, 0, stream>>>(xb, wqkv, qkv, 4096, 6144, 2048);
  rope_k<<<4096, 256, 0, stream>>>(qkv, fc, fs);
  attn_fwd<<<512, 256, 0, stream>>>(qkv, fc, fs, aout);
  gemm_nt_2ph<1><<<256, 512, 0, stream>>>(aout, wob, d_out, 4096, 2048, 2048);
}